// Round 9
// baseline (313.606 us; speedup 1.0000x reference)
//
#include <hip/hip_runtime.h>

#define LOG2E 1.44269504f
#define C_QSCALE 0.360673760f   // 0.25 * log2(e)
#define C_SHIFT  34.6246810f    // 24 * log2(e)
typedef unsigned short u16;
typedef short bf16x8 __attribute__((ext_vector_type(8)));
typedef float f32x4 __attribute__((ext_vector_type(4)));
typedef unsigned short u16x4 __attribute__((ext_vector_type(4)));

#define BB 2
#define LL 2048
#define HH 1024
#define NH 16
#define HD 64
#define ML (BB*LL)   // 4096 rows total

__device__ __forceinline__ u16 f2bf(float f) {   // round-to-nearest-even
  union { float f; unsigned u; } v; v.f = f;
  unsigned r = v.u + 0x7FFFu + ((v.u >> 16) & 1u);
  return (u16)(r >> 16);
}
__device__ __forceinline__ u16 f2bf_trunc(float f) {
  union { float f; unsigned u; } v; v.f = f;
  return (u16)(v.u >> 16);
}
__device__ __forceinline__ float bf2f(u16 u) {
  union { unsigned u; float f; } v; v.u = ((unsigned)u) << 16;
  return v.f;
}
__device__ __forceinline__ void gload_lds16(const u16* g, u16* l) {
  __builtin_amdgcn_global_load_lds((const __attribute__((address_space(1))) void*)g,
                                   (__attribute__((address_space(3))) void*)l, 16, 0, 0);
}

// ---------------- merged: E fp32->bf16 convert  +  W transpose->bf16 ----------------
__global__ __launch_bounds__(256) void k_prep(const float* __restrict__ E, u16* __restrict__ X,
                                              const float* W0, const float* W1,
                                              const float* W2, const float* W3,
                                              u16* __restrict__ WT) {
  __shared__ __align__(16) u16 T[64*72];
  if (blockIdx.x < 2048) {                       // convert branch
    int idx = (blockIdx.x * 256 + threadIdx.x) * 8;
    float4 a = *(const float4*)(E + idx);
    float4 b = *(const float4*)(E + idx + 4);
    bf16x8 o;
    o[0]=f2bf(a.x); o[1]=f2bf(a.y); o[2]=f2bf(a.z); o[3]=f2bf(a.w);
    o[4]=f2bf(b.x); o[5]=f2bf(b.y); o[6]=f2bf(b.z); o[7]=f2bf(b.w);
    *(bf16x8*)(X + idx) = o;
    return;
  }
  int bz = blockIdx.x - 2048;
  int z = bz >> 8, rem = bz & 255, bx = rem & 15, by = rem >> 4;
  const float* W = (z==0)?W0:(z==1)?W1:(z==2)?W2:W3;
  u16* dst = WT + (size_t)z * HH * HH;
  int t = threadIdx.x;
  int n0 = bx * 64, k0 = by * 64;
  int kl = t >> 2, nc = t & 3;
  #pragma unroll
  for (int u = 0; u < 4; ++u) {
    float4 v = *(const float4*)(W + (size_t)(k0 + kl) * HH + n0 + nc*16 + u*4);
    int nb = nc*16 + u*4;
    T[(nb+0)*72 + kl] = f2bf(v.x);
    T[(nb+1)*72 + kl] = f2bf(v.y);
    T[(nb+2)*72 + kl] = f2bf(v.z);
    T[(nb+3)*72 + kl] = f2bf(v.w);
  }
  __syncthreads();
  int nl = t >> 2, kc = (t & 3) * 16;
  #pragma unroll
  for (int e = 0; e < 2; ++e) {
    bf16x8 v = *(const bf16x8*)(T + nl*72 + kc + e*8);
    *(bf16x8*)(dst + (size_t)(n0+nl)*HH + k0 + kc + e*8) = v;
  }
}

// ---------------- 128x128x(K=1024) bf16 QKV GEMM, dbuf DMA prefetch ----
// z=bn0>>10: 0=Q swapped, 1=K normal, 2=V swapped
//   Q -> QH [bh][l][d]; K,V -> KV tiles [bh][t][K^T-sw 8KB | V-sw 8KB]
__global__ __launch_bounds__(256) void k_gemm(const u16* __restrict__ A, const u16* __restrict__ Bt,
                                              const float* __restrict__ b0, const float* __restrict__ b1,
                                              const float* __restrict__ b2,
                                              u16* __restrict__ QH, u16* __restrict__ KV) {
  __shared__ __align__(16) u16 As[2][128*32];
  __shared__ __align__(16) u16 Bs[2][128*32];
  int tid = threadIdx.x;
  int lane = tid & 63, w = tid >> 6;
  int c = lane & 15, g = lane >> 4;
  int bn0 = blockIdx.x * 128, bm0 = blockIdx.y * 128;
  int wm0 = (w >> 1) * 64, wn0 = (w & 1) * 64;
  int z = bn0 >> 10;
  bool swapd = (z != 1);                         // swapped: As<-weights, Bs<-tokens
  const u16* srcA = swapd ? Bt : A;
  const u16* srcB = swapd ? A : Bt;
  int baseA = swapd ? bn0 : bm0;
  int baseB = swapd ? bm0 : bn0;

  f32x4 acc[4][4];
  #pragma unroll
  for (int mt = 0; mt < 4; ++mt)
    #pragma unroll
    for (int nt = 0; nt < 4; ++nt)
      acc[mt][nt] = (f32x4){0.f,0.f,0.f,0.f};

  #pragma unroll
  for (int it = 0; it < 2; ++it) {               // prologue: stage kt=0 -> buf0
    int ch = tid + it*256, row = ch >> 2, col = (ch & 3) * 8;
    gload_lds16(srcA + (size_t)(baseA + row) * HH + col, &As[0][ch*8]);
    gload_lds16(srcB + (size_t)(baseB + row) * HH + col, &Bs[0][ch*8]);
  }
  for (int kt = 0; kt < 32; ++kt) {
    __syncthreads();                             // drains my tile-kt DMA (in flight 1 tile)
    int cb = kt & 1;
    if (kt < 31) {                               // prefetch kt+1 while computing kt
      int k0 = (kt + 1) * 32, nb = (kt + 1) & 1;
      #pragma unroll
      for (int it = 0; it < 2; ++it) {
        int ch = tid + it*256, row = ch >> 2, col = (ch & 3) * 8;
        gload_lds16(srcA + (size_t)(baseA + row) * HH + k0 + col, &As[nb][ch*8]);
        gload_lds16(srcB + (size_t)(baseB + row) * HH + k0 + col, &Bs[nb][ch*8]);
      }
    }
    bf16x8 af[4], bfr[4];
    #pragma unroll
    for (int i = 0; i < 4; ++i) {
      af[i]  = *(const bf16x8*)(&As[cb][0] + (wm0 + i*16 + c)*32 + g*8);
      bfr[i] = *(const bf16x8*)(&Bs[cb][0] + (wn0 + i*16 + c)*32 + g*8);
    }
    #pragma unroll
    for (int mt = 0; mt < 4; ++mt)
      #pragma unroll
      for (int nt = 0; nt < 4; ++nt)
        acc[mt][nt] = __builtin_amdgcn_mfma_f32_16x16x32_bf16(af[mt], bfr[nt], acc[mt][nt], 0, 0, 0);
  }

  if (z == 1) {                                  // K, normal orientation -> K^T-sw tiles
    #pragma unroll
    for (int nt = 0; nt < 4; ++nt) {
      int n = bn0 + wn0 + nt*16 + c;
      int nn = n & 1023, h = nn >> 6, d = nn & 63;
      float bv = b1[nn];
      #pragma unroll
      for (int mt = 0; mt < 4; ++mt) {
        int m0 = bm0 + wm0 + mt*16 + 4*g;
        int b = m0 >> 11, keyl = m0 & 2047;
        int tt = keyl >> 6, chunk = (keyl >> 3) & 7, s = keyl & 7;
        u16x4 pk;
        #pragma unroll
        for (int r = 0; r < 4; ++r) pk[r] = f2bf(acc[mt][nt][r] + bv);
        *(u16x4*)(KV + ((size_t)((b*NH + h)*32 + tt))*8192 + d*64 + ((chunk ^ (d & 7))*8) + s) = pk;
      }
    }
  } else {                                       // Q / V, swapped orientation
    #pragma unroll
    for (int mt = 0; mt < 4; ++mt) {
      int nidx0 = bn0 + wm0 + mt*16 + 4*g;
      int nn0 = nidx0 & 1023, h = nn0 >> 6, d0 = nn0 & 63;
      const float* bp = (z == 0) ? b0 : b2;
      float4 bv = *(const float4*)(bp + nn0);
      #pragma unroll
      for (int nt = 0; nt < 4; ++nt) {
        int tok = bm0 + wn0 + nt*16 + c;
        int b = tok >> 11, l = tok & 2047;
        u16x4 o;
        o[0] = f2bf(acc[mt][nt][0] + bv.x);
        o[1] = f2bf(acc[mt][nt][1] + bv.y);
        o[2] = f2bf(acc[mt][nt][2] + bv.z);
        o[3] = f2bf(acc[mt][nt][3] + bv.w);
        if (z == 0) {
          *(u16x4*)(QH + (((size_t)(b*NH + h)) * LL + l) * HD + d0) = o;
        } else {
          int tt = l >> 6;
          *(u16x4*)(KV + ((size_t)((b*NH + h)*32 + tt))*8192 + 4096
                    + (l & 63)*64 + (((d0 >> 3) ^ (l & 7))*8) + (d0 & 7)) = o;
        }
      }
    }
  }
}

// ---------------- out-proj GEMM: 64 tokens x 128 n per block, dbuf DMA ----------------
__global__ __launch_bounds__(256) void k_gemm_o(const u16* __restrict__ ATT, const u16* __restrict__ Wt,
                                                const float* __restrict__ bias,
                                                float* __restrict__ outf) {
  __shared__ __align__(16) u16 As[2][128*32];    // weights: n rows x k
  __shared__ __align__(16) u16 Bs[2][64*32];     // tokens
  int tid = threadIdx.x;
  int lane = tid & 63, w = tid >> 6;
  int c = lane & 15, g = lane >> 4;
  int bn0 = blockIdx.x * 128, bm0 = blockIdx.y * 64;
  int wm0 = (w >> 1) * 64, wn0 = (w & 1) * 32;

  f32x4 acc[4][2];
  #pragma unroll
  for (int mt = 0; mt < 4; ++mt)
    #pragma unroll
    for (int nt = 0; nt < 2; ++nt)
      acc[mt][nt] = (f32x4){0.f,0.f,0.f,0.f};

  #pragma unroll
  for (int it = 0; it < 2; ++it) {               // prologue: As 512 chunks
    int ch = tid + it*256, row = ch >> 2, col = (ch & 3) * 8;
    gload_lds16(Wt + (size_t)(bn0 + row) * HH + col, &As[0][ch*8]);
  }
  { int row = tid >> 2, col = (tid & 3) * 8;     // Bs 256 chunks
    gload_lds16(ATT + (size_t)(bm0 + row) * HH + col, &Bs[0][tid*8]); }

  for (int kt = 0; kt < 32; ++kt) {
    __syncthreads();
    int cb = kt & 1;
    if (kt < 31) {
      int k0 = (kt + 1) * 32, nb = (kt + 1) & 1;
      #pragma unroll
      for (int it = 0; it < 2; ++it) {
        int ch = tid + it*256, row = ch >> 2, col = (ch & 3) * 8;
        gload_lds16(Wt + (size_t)(bn0 + row) * HH + k0 + col, &As[nb][ch*8]);
      }
      int row = tid >> 2, col = (tid & 3) * 8;
      gload_lds16(ATT + (size_t)(bm0 + row) * HH + k0 + col, &Bs[nb][tid*8]);
    }
    bf16x8 af[4], bfr[2];
    #pragma unroll
    for (int i = 0; i < 4; ++i)
      af[i] = *(const bf16x8*)(&As[cb][0] + (wm0 + i*16 + c)*32 + g*8);
    #pragma unroll
    for (int j = 0; j < 2; ++j)
      bfr[j] = *(const bf16x8*)(&Bs[cb][0] + (wn0 + j*16 + c)*32 + g*8);
    #pragma unroll
    for (int mt = 0; mt < 4; ++mt)
      #pragma unroll
      for (int nt = 0; nt < 2; ++nt)
        acc[mt][nt] = __builtin_amdgcn_mfma_f32_16x16x32_bf16(af[mt], bfr[nt], acc[mt][nt], 0, 0, 0);
  }
  #pragma unroll
  for (int mt = 0; mt < 4; ++mt) {
    int n0 = bn0 + wm0 + mt*16 + 4*g;
    float4 bv = *(const float4*)(bias + n0);
    #pragma unroll
    for (int nt = 0; nt < 2; ++nt) {
      int tok = bm0 + wn0 + nt*16 + c;
      float4 o;
      o.x = acc[mt][nt][0] + bv.x;
      o.y = acc[mt][nt][1] + bv.y;
      o.z = acc[mt][nt][2] + bv.z;
      o.w = acc[mt][nt][3] + bv.w;
      *(float4*)(outf + (size_t)tok * HH + n0) = o;
    }
  }
}

// ---------------- flash attention: 512 thr, 8 waves x 32q = 256 q/block, key-split x2 ----
// 32 waves/CU (4 blocks x 8 waves; VGPR<=64 via launch_bounds(512,8), LDS 34.4KB).
// Serialized qi through per-wave 16x72 P buffer keeps VGPR under 64.
// Fixed-shift softmax -> partial O (bf16) + l (fp32 in d_out); k_combine normalizes.
__global__ __launch_bounds__(512, 8) void k_attn(const u16* __restrict__ QH, const u16* __restrict__ KV,
                                                 const float* __restrict__ mask,
                                                 u16* __restrict__ PO0, u16* __restrict__ PO1,
                                                 float* __restrict__ PL) {
  __shared__ __align__(16) u16 sKV[8192];       // [0,4096) K^T-sw, [4096,8192) V-sw
  __shared__ __align__(16) u16 sP[8][16*72];    // per-wave, 16 q-rows at a time
  int tid = threadIdx.x;
  int lane = tid & 63, w = tid >> 6;
  int c = lane & 15, g = lane >> 4;
  int z = blockIdx.y;                           // key half
  int bh = blockIdx.z, b = bh >> 4;
  int q0 = blockIdx.x * 256 + w * 32;           // this wave's 32 q-rows
  size_t qbase = (size_t)bh * LL * HD;
  const u16* kvg = KV + (size_t)bh * 32 * 8192 + (size_t)z * 16 * 8192;
  const float* mptr = mask + b * LL + z * 1024;
  u16* pw = &sP[w][0];

  bf16x8 aq[2][2];
  #pragma unroll
  for (int qi = 0; qi < 2; ++qi)
    #pragma unroll
    for (int ks = 0; ks < 2; ++ks)
      aq[qi][ks] = *(const bf16x8*)(QH + qbase + (size_t)(q0 + qi*16 + c) * HD + ks*32 + g*8);

  bf16x8 ones;
  #pragma unroll
  for (int i = 0; i < 8; ++i) ones[i] = (short)0x3F80;   // bf16 1.0

  f32x4 O[2][4], lac[2];
  #pragma unroll
  for (int qi = 0; qi < 2; ++qi) {
    lac[qi] = (f32x4){0.f,0.f,0.f,0.f};
    #pragma unroll
    for (int dt = 0; dt < 4; ++dt) O[qi][dt] = (f32x4){0.f,0.f,0.f,0.f};
  }

  for (int tt = 0; tt < 16; ++tt) {
    __syncthreads();                            // all waves done reading sKV
    #pragma unroll
    for (int it = 0; it < 2; ++it) {            // identity-copy DMA, 16 KB tile, 512 thr
      int i = (tid + it*512) * 8;
      gload_lds16(kvg + (size_t)tt*8192 + i, sKV + i);
    }
    __syncthreads();                            // vmcnt(0) drain -> tile ready

    int kv0 = tt * 64;
    float mt4[4];
    #pragma unroll
    for (int nt = 0; nt < 4; ++nt)
      mt4[nt] = fmaf(mptr[kv0 + nt*16 + c], LOG2E, -C_SHIFT);

    #pragma unroll
    for (int qi = 0; qi < 2; ++qi) {            // two q-subtiles through one P buffer
      #pragma unroll
      for (int nt = 0; nt < 4; ++nt) {          // S = Q*V^T, P = exp2(...)
        int vrow = nt*16 + c;
        bf16x8 vb0 = *(const bf16x8*)(sKV + 4096 + vrow*64 + ((g ^ (c & 7))*8));
        bf16x8 vb1 = *(const bf16x8*)(sKV + 4096 + vrow*64 + (((4 + g) ^ (c & 7))*8));
        f32x4 sa = (f32x4){0.f,0.f,0.f,0.f};
        sa = __builtin_amdgcn_mfma_f32_16x16x32_bf16(aq[qi][0], vb0, sa, 0,0,0);
        sa = __builtin_amdgcn_mfma_f32_16x16x32_bf16(aq[qi][1], vb1, sa, 0,0,0);
        #pragma unroll
        for (int r = 0; r < 4; ++r)
          pw[(4*g + r)*72 + nt*16 + c] = f2bf_trunc(exp2f(fmaf(sa[r], C_QSCALE, mt4[nt])));
      }
      bf16x8 ap0 = *(const bf16x8*)(pw + c*72 + g*8);        // P as B-frags
      bf16x8 ap1 = *(const bf16x8*)(pw + c*72 + 32 + g*8);
      lac[qi] = __builtin_amdgcn_mfma_f32_16x16x32_bf16(ones, ap0, lac[qi], 0,0,0);
      lac[qi] = __builtin_amdgcn_mfma_f32_16x16x32_bf16(ones, ap1, lac[qi], 0,0,0);
      #pragma unroll
      for (int dt = 0; dt < 4; ++dt) {          // O^T += K^T-frag * P  (d-major out)
        int d = dt*16 + c;
        bf16x8 bk0 = *(const bf16x8*)(sKV + d*64 + ((g ^ (c & 7))*8));
        bf16x8 bk1 = *(const bf16x8*)(sKV + d*64 + (((4 + g) ^ (c & 7))*8));
        O[qi][dt] = __builtin_amdgcn_mfma_f32_16x16x32_bf16(bk0, ap0, O[qi][dt], 0,0,0);
        O[qi][dt] = __builtin_amdgcn_mfma_f32_16x16x32_bf16(bk1, ap1, O[qi][dt], 0,0,0);
      }
    }
  }
  u16* POp = (z == 0) ? PO0 : PO1;
  #pragma unroll
  for (int qi = 0; qi < 2; ++qi) {
    int q = q0 + qi*16 + c;
    size_t qrow = (size_t)bh * LL + q;
    if (g == 0) PL[(size_t)(z*32 + bh) * LL + q] = lac[qi][0];   // col-sums: rows equal
    #pragma unroll
    for (int dt = 0; dt < 4; ++dt) {
      u16x4 o;
      #pragma unroll
      for (int r = 0; r < 4; ++r) o[r] = f2bf(O[qi][dt][r]);
      *(u16x4*)(POp + qrow*HD + dt*16 + 4*g) = o;
    }
  }
}

// ---------------- combine key-half partials -> ATT bf16 ----------------
__global__ __launch_bounds__(256) void k_combine(const u16* __restrict__ PO0,
                                                 const u16* __restrict__ PO1,
                                                 const float* __restrict__ PL,
                                                 u16* __restrict__ ATT) {
  int bh = blockIdx.y, b = bh >> 4, h = bh & 15;
  int q = blockIdx.x * 128 + (threadIdx.x >> 1);
  int dh = (threadIdx.x & 1) * 32;
  size_t r0 = ((size_t)bh * LL + q) * HD + dh;
  float inv = 1.0f / (PL[(size_t)bh * LL + q] + PL[(size_t)(32 + bh) * LL + q]);
  u16* dst = ATT + ((size_t)(b*LL + q)) * HH + h*HD + dh;
  #pragma unroll
  for (int e = 0; e < 4; ++e) {
    bf16x8 a0 = *(const bf16x8*)(PO0 + r0 + e*8);
    bf16x8 a1 = *(const bf16x8*)(PO1 + r0 + e*8);
    bf16x8 o;
    #pragma unroll
    for (int i = 0; i < 8; ++i)
      o[i] = (short)f2bf((bf2f((u16)a0[i]) + bf2f((u16)a1[i])) * inv);
    *(bf16x8*)(dst + e*8) = o;
  }
}

// ---------------- residual + LayerNorm -> fp32 out ----------------
__global__ __launch_bounds__(256) void k_ln(const float* __restrict__ OF, const float* __restrict__ E,
                                            const float* __restrict__ gamma, const float* __restrict__ beta,
                                            float* __restrict__ out) {
  int row = blockIdx.x;
  int tid = threadIdx.x, lane = tid & 63, w = tid >> 6;
  size_t basei = (size_t)row * HH + tid*4;
  float4 a = *(const float4*)(OF + basei);
  float4 e = *(const float4*)(E + basei);
  float x0 = a.x + e.x, x1 = a.y + e.y, x2 = a.z + e.z, x3 = a.w + e.w;
  float s1 = x0+x1+x2+x3;
  float s2 = x0*x0+x1*x1+x2*x2+x3*x3;
  #pragma unroll
  for (int off = 32; off; off >>= 1) { s1 += __shfl_xor(s1, off); s2 += __shfl_xor(s2, off); }
  __shared__ float r1[4], r2[4];
  if (lane == 0) { r1[w] = s1; r2[w] = s2; }
  __syncthreads();
  s1 = r1[0]+r1[1]+r1[2]+r1[3];
  s2 = r2[0]+r2[1]+r2[2]+r2[3];
  float mu = s1 * (1.0f/HH);
  float var = s2 * (1.0f/HH) - mu*mu;
  float rs = rsqrtf(fmaxf(var, 0.f) + 1e-12f);
  int colb = tid*4;
  float4 gm = *(const float4*)(gamma + colb);
  float4 bt = *(const float4*)(beta + colb);
  float4 o;
  o.x = (x0-mu)*rs*gm.x + bt.x;
  o.y = (x1-mu)*rs*gm.y + bt.y;
  o.z = (x2-mu)*rs*gm.z + bt.z;
  o.w = (x3-mu)*rs*gm.w + bt.w;
  *(float4*)(out + basei) = o;
}

extern "C" void kernel_launch(void* const* d_in, const int* in_sizes, int n_in,
                              void* d_out, int out_size, void* d_ws, size_t ws_size,
                              hipStream_t stream) {
  const float* E    = (const float*)d_in[0];
  const float* mask = (const float*)d_in[1];
  const float* Wq   = (const float*)d_in[2];
  const float* bq   = (const float*)d_in[3];
  const float* Wk   = (const float*)d_in[4];
  const float* bk   = (const float*)d_in[5];
  const float* Wv   = (const float*)d_in[6];
  const float* bv   = (const float*)d_in[7];
  const float* Wo   = (const float*)d_in[8];
  const float* bo   = (const float*)d_in[9];
  const float* gam  = (const float*)d_in[10];
  const float* bet  = (const float*)d_in[11];

  const size_t MH = (size_t)ML * HH;      // 4M elems
  u16* XBF = (u16*)d_ws;                  // 8 MB bf16 embeddings (dead after QKV gemm)
  u16* WT  = XBF + MH;                    // 8 MB: Wq^T,Wk^T,Wv^T,Wo^T bf16 [n][k]
  u16* QH  = WT + 4*(size_t)HH*HH;        // 8 MB, [bh][l][d]
  u16* KV  = QH + MH;                     // 16 MB: [bh][32 tiles][K^T-sw 8KB | V-sw 8KB]
  u16* ATT = KV + 2*MH;                   // 8 MB, [b*L][h*64+d]
  u16* PO0 = ATT + MH;                    // 8 MB partial O, key half 0
  u16* PO1 = PO0 + MH;                    // 8 MB partial O, key half 1
  float* out = (float*)d_out;
  float* PL = out;                        // 512 KB partial l in d_out (k_ln overwrites later)
  float* OF = (float*)PO0;                // 16 MB fp32, overlays PO0+PO1 (dead after combine)

  k_prep<<<dim3(3072), 256, 0, stream>>>(E, XBF, Wq, Wk, Wv, Wo, WT);
  k_gemm<<<dim3(24,32), 256, 0, stream>>>(XBF, WT, bq, bk, bv, QH, KV);
  k_attn<<<dim3(8,2,32), 512, 0, stream>>>(QH, KV, mask, PO0, PO1, PL);
  k_combine<<<dim3(16,32), 256, 0, stream>>>(PO0, PO1, PL, ATT);
  k_gemm_o<<<dim3(8,64), 256, 0, stream>>>(ATT, WT + 3*(size_t)HH*HH, bo, OF);
  k_ln<<<dim3(ML), 256, 0, stream>>>(OF, E, gam, bet, out);
}

// Round 10
// 302.005 us; speedup vs baseline: 1.0384x; 1.0384x over previous
//
#include <hip/hip_runtime.h>

#define LOG2E 1.44269504f
#define C_QSCALE 0.360673760f   // 0.25 * log2(e)
#define C_SHIFT  34.6246810f    // 24 * log2(e)
typedef unsigned short u16;
typedef short bf16x8 __attribute__((ext_vector_type(8)));
typedef float f32x4 __attribute__((ext_vector_type(4)));
typedef unsigned short u16x4 __attribute__((ext_vector_type(4)));

#define BB 2
#define LL 2048
#define HH 1024
#define NH 16
#define HD 64
#define ML (BB*LL)   // 4096 rows total

__device__ __forceinline__ u16 f2bf(float f) {   // round-to-nearest-even
  union { float f; unsigned u; } v; v.f = f;
  unsigned r = v.u + 0x7FFFu + ((v.u >> 16) & 1u);
  return (u16)(r >> 16);
}
__device__ __forceinline__ u16 f2bf_trunc(float f) {
  union { float f; unsigned u; } v; v.f = f;
  return (u16)(v.u >> 16);
}
__device__ __forceinline__ float bf2f(u16 u) {
  union { unsigned u; float f; } v; v.u = ((unsigned)u) << 16;
  return v.f;
}
__device__ __forceinline__ void gload_lds16(const u16* g, u16* l) {
  __builtin_amdgcn_global_load_lds((const __attribute__((address_space(1))) void*)g,
                                   (__attribute__((address_space(3))) void*)l, 16, 0, 0);
}

// ---------------- merged: E fp32->bf16 convert  +  W transpose->bf16 ----------------
__global__ __launch_bounds__(256) void k_prep(const float* __restrict__ E, u16* __restrict__ X,
                                              const float* W0, const float* W1,
                                              const float* W2, const float* W3,
                                              u16* __restrict__ WT) {
  __shared__ __align__(16) u16 T[64*72];
  if (blockIdx.x < 2048) {                       // convert branch
    int idx = (blockIdx.x * 256 + threadIdx.x) * 8;
    float4 a = *(const float4*)(E + idx);
    float4 b = *(const float4*)(E + idx + 4);
    bf16x8 o;
    o[0]=f2bf(a.x); o[1]=f2bf(a.y); o[2]=f2bf(a.z); o[3]=f2bf(a.w);
    o[4]=f2bf(b.x); o[5]=f2bf(b.y); o[6]=f2bf(b.z); o[7]=f2bf(b.w);
    *(bf16x8*)(X + idx) = o;
    return;
  }
  int bz = blockIdx.x - 2048;
  int z = bz >> 8, rem = bz & 255, bx = rem & 15, by = rem >> 4;
  const float* W = (z==0)?W0:(z==1)?W1:(z==2)?W2:W3;
  u16* dst = WT + (size_t)z * HH * HH;
  int t = threadIdx.x;
  int n0 = bx * 64, k0 = by * 64;
  int kl = t >> 2, nc = t & 3;
  #pragma unroll
  for (int u = 0; u < 4; ++u) {
    float4 v = *(const float4*)(W + (size_t)(k0 + kl) * HH + n0 + nc*16 + u*4);
    int nb = nc*16 + u*4;
    T[(nb+0)*72 + kl] = f2bf(v.x);
    T[(nb+1)*72 + kl] = f2bf(v.y);
    T[(nb+2)*72 + kl] = f2bf(v.z);
    T[(nb+3)*72 + kl] = f2bf(v.w);
  }
  __syncthreads();
  int nl = t >> 2, kc = (t & 3) * 16;
  #pragma unroll
  for (int e = 0; e < 2; ++e) {
    bf16x8 v = *(const bf16x8*)(T + nl*72 + kc + e*8);
    *(bf16x8*)(dst + (size_t)(n0+nl)*HH + k0 + kc + e*8) = v;
  }
}

// ---------------- 128x128x(K=1024) bf16 QKV GEMM, dbuf DMA prefetch ----
// z=bn0>>10: 0=Q swapped, 1=K normal, 2=V swapped
//   Q -> QH [bh][l][d]; K,V -> KV tiles [bh][t][K^T-sw 8KB | V-sw 8KB]
__global__ __launch_bounds__(256) void k_gemm(const u16* __restrict__ A, const u16* __restrict__ Bt,
                                              const float* __restrict__ b0, const float* __restrict__ b1,
                                              const float* __restrict__ b2,
                                              u16* __restrict__ QH, u16* __restrict__ KV) {
  __shared__ __align__(16) u16 As[2][128*32];
  __shared__ __align__(16) u16 Bs[2][128*32];
  int tid = threadIdx.x;
  int lane = tid & 63, w = tid >> 6;
  int c = lane & 15, g = lane >> 4;
  int bn0 = blockIdx.x * 128, bm0 = blockIdx.y * 128;
  int wm0 = (w >> 1) * 64, wn0 = (w & 1) * 64;
  int z = bn0 >> 10;
  bool swapd = (z != 1);                         // swapped: As<-weights, Bs<-tokens
  const u16* srcA = swapd ? Bt : A;
  const u16* srcB = swapd ? A : Bt;
  int baseA = swapd ? bn0 : bm0;
  int baseB = swapd ? bm0 : bn0;

  f32x4 acc[4][4];
  #pragma unroll
  for (int mt = 0; mt < 4; ++mt)
    #pragma unroll
    for (int nt = 0; nt < 4; ++nt)
      acc[mt][nt] = (f32x4){0.f,0.f,0.f,0.f};

  #pragma unroll
  for (int it = 0; it < 2; ++it) {               // prologue: stage kt=0 -> buf0
    int ch = tid + it*256, row = ch >> 2, col = (ch & 3) * 8;
    gload_lds16(srcA + (size_t)(baseA + row) * HH + col, &As[0][ch*8]);
    gload_lds16(srcB + (size_t)(baseB + row) * HH + col, &Bs[0][ch*8]);
  }
  for (int kt = 0; kt < 32; ++kt) {
    __syncthreads();                             // drains my tile-kt DMA (in flight 1 tile)
    int cb = kt & 1;
    if (kt < 31) {                               // prefetch kt+1 while computing kt
      int k0 = (kt + 1) * 32, nb = (kt + 1) & 1;
      #pragma unroll
      for (int it = 0; it < 2; ++it) {
        int ch = tid + it*256, row = ch >> 2, col = (ch & 3) * 8;
        gload_lds16(srcA + (size_t)(baseA + row) * HH + k0 + col, &As[nb][ch*8]);
        gload_lds16(srcB + (size_t)(baseB + row) * HH + k0 + col, &Bs[nb][ch*8]);
      }
    }
    bf16x8 af[4], bfr[4];
    #pragma unroll
    for (int i = 0; i < 4; ++i) {
      af[i]  = *(const bf16x8*)(&As[cb][0] + (wm0 + i*16 + c)*32 + g*8);
      bfr[i] = *(const bf16x8*)(&Bs[cb][0] + (wn0 + i*16 + c)*32 + g*8);
    }
    #pragma unroll
    for (int mt = 0; mt < 4; ++mt)
      #pragma unroll
      for (int nt = 0; nt < 4; ++nt)
        acc[mt][nt] = __builtin_amdgcn_mfma_f32_16x16x32_bf16(af[mt], bfr[nt], acc[mt][nt], 0, 0, 0);
  }

  if (z == 1) {                                  // K, normal orientation -> K^T-sw tiles
    #pragma unroll
    for (int nt = 0; nt < 4; ++nt) {
      int n = bn0 + wn0 + nt*16 + c;
      int nn = n & 1023, h = nn >> 6, d = nn & 63;
      float bv = b1[nn];
      #pragma unroll
      for (int mt = 0; mt < 4; ++mt) {
        int m0 = bm0 + wm0 + mt*16 + 4*g;
        int b = m0 >> 11, keyl = m0 & 2047;
        int tt = keyl >> 6, chunk = (keyl >> 3) & 7, s = keyl & 7;
        u16x4 pk;
        #pragma unroll
        for (int r = 0; r < 4; ++r) pk[r] = f2bf(acc[mt][nt][r] + bv);
        *(u16x4*)(KV + ((size_t)((b*NH + h)*32 + tt))*8192 + d*64 + ((chunk ^ (d & 7))*8) + s) = pk;
      }
    }
  } else {                                       // Q / V, swapped orientation
    #pragma unroll
    for (int mt = 0; mt < 4; ++mt) {
      int nidx0 = bn0 + wm0 + mt*16 + 4*g;
      int nn0 = nidx0 & 1023, h = nn0 >> 6, d0 = nn0 & 63;
      const float* bp = (z == 0) ? b0 : b2;
      float4 bv = *(const float4*)(bp + nn0);
      #pragma unroll
      for (int nt = 0; nt < 4; ++nt) {
        int tok = bm0 + wn0 + nt*16 + c;
        int b = tok >> 11, l = tok & 2047;
        u16x4 o;
        o[0] = f2bf(acc[mt][nt][0] + bv.x);
        o[1] = f2bf(acc[mt][nt][1] + bv.y);
        o[2] = f2bf(acc[mt][nt][2] + bv.z);
        o[3] = f2bf(acc[mt][nt][3] + bv.w);
        if (z == 0) {
          *(u16x4*)(QH + (((size_t)(b*NH + h)) * LL + l) * HD + d0) = o;
        } else {
          int tt = l >> 6;
          *(u16x4*)(KV + ((size_t)((b*NH + h)*32 + tt))*8192 + 4096
                    + (l & 63)*64 + (((d0 >> 3) ^ (l & 7))*8) + (d0 & 7)) = o;
        }
      }
    }
  }
}

// ---------------- out-proj GEMM: 64 tokens x 128 n per block, dbuf DMA ----------------
__global__ __launch_bounds__(256) void k_gemm_o(const u16* __restrict__ ATT, const u16* __restrict__ Wt,
                                                const float* __restrict__ bias,
                                                float* __restrict__ outf) {
  __shared__ __align__(16) u16 As[2][128*32];    // weights: n rows x k
  __shared__ __align__(16) u16 Bs[2][64*32];     // tokens
  int tid = threadIdx.x;
  int lane = tid & 63, w = tid >> 6;
  int c = lane & 15, g = lane >> 4;
  int bn0 = blockIdx.x * 128, bm0 = blockIdx.y * 64;
  int wm0 = (w >> 1) * 64, wn0 = (w & 1) * 32;

  f32x4 acc[4][2];
  #pragma unroll
  for (int mt = 0; mt < 4; ++mt)
    #pragma unroll
    for (int nt = 0; nt < 2; ++nt)
      acc[mt][nt] = (f32x4){0.f,0.f,0.f,0.f};

  #pragma unroll
  for (int it = 0; it < 2; ++it) {               // prologue: As 512 chunks
    int ch = tid + it*256, row = ch >> 2, col = (ch & 3) * 8;
    gload_lds16(Wt + (size_t)(bn0 + row) * HH + col, &As[0][ch*8]);
  }
  { int row = tid >> 2, col = (tid & 3) * 8;     // Bs 256 chunks
    gload_lds16(ATT + (size_t)(bm0 + row) * HH + col, &Bs[0][tid*8]); }

  for (int kt = 0; kt < 32; ++kt) {
    __syncthreads();
    int cb = kt & 1;
    if (kt < 31) {
      int k0 = (kt + 1) * 32, nb = (kt + 1) & 1;
      #pragma unroll
      for (int it = 0; it < 2; ++it) {
        int ch = tid + it*256, row = ch >> 2, col = (ch & 3) * 8;
        gload_lds16(Wt + (size_t)(bn0 + row) * HH + k0 + col, &As[nb][ch*8]);
      }
      int row = tid >> 2, col = (tid & 3) * 8;
      gload_lds16(ATT + (size_t)(bm0 + row) * HH + k0 + col, &Bs[nb][tid*8]);
    }
    bf16x8 af[4], bfr[2];
    #pragma unroll
    for (int i = 0; i < 4; ++i)
      af[i] = *(const bf16x8*)(&As[cb][0] + (wm0 + i*16 + c)*32 + g*8);
    #pragma unroll
    for (int j = 0; j < 2; ++j)
      bfr[j] = *(const bf16x8*)(&Bs[cb][0] + (wn0 + j*16 + c)*32 + g*8);
    #pragma unroll
    for (int mt = 0; mt < 4; ++mt)
      #pragma unroll
      for (int nt = 0; nt < 2; ++nt)
        acc[mt][nt] = __builtin_amdgcn_mfma_f32_16x16x32_bf16(af[mt], bfr[nt], acc[mt][nt], 0, 0, 0);
  }
  #pragma unroll
  for (int mt = 0; mt < 4; ++mt) {
    int n0 = bn0 + wm0 + mt*16 + 4*g;
    float4 bv = *(const float4*)(bias + n0);
    #pragma unroll
    for (int nt = 0; nt < 2; ++nt) {
      int tok = bm0 + wn0 + nt*16 + c;
      float4 o;
      o.x = acc[mt][nt][0] + bv.x;
      o.y = acc[mt][nt][1] + bv.y;
      o.z = acc[mt][nt][2] + bv.z;
      o.w = acc[mt][nt][3] + bv.w;
      *(float4*)(outf + (size_t)tok * HH + n0) = o;
    }
  }
}

// ---------------- flash attention: 512 thr = 8 waves x 32q, key-split x3 ----------------
// r6's parallel-qi body verbatim; 768 blocks = 3/CU (LDS 53.2KB), 24 waves/CU.
// launch_bounds(512,6) caps VGPR at 85 (body needs ~60; r9's (512,8) spilled).
// Fixed-shift softmax -> partial O (bf16) + l (fp32 in d_out); k_combine normalizes.
__global__ __launch_bounds__(512, 6) void k_attn(const u16* __restrict__ QH, const u16* __restrict__ KV,
                                                 const float* __restrict__ mask,
                                                 u16* __restrict__ PO0, u16* __restrict__ PO1,
                                                 u16* __restrict__ PO2, float* __restrict__ PL) {
  __shared__ __align__(16) u16 sKV[8192];       // [0,4096) K^T-sw, [4096,8192) V-sw
  __shared__ __align__(16) u16 sP[8][32*72];    // per-wave P buffer (32 q-rows)
  int tid = threadIdx.x;
  int lane = tid & 63, w = tid >> 6;
  int c = lane & 15, g = lane >> 4;
  int z = blockIdx.y;                           // key third
  int bh = blockIdx.z, b = bh >> 4;
  int q0 = blockIdx.x * 256 + w * 32;           // this wave's 32 q-rows
  size_t qbase = (size_t)bh * LL * HD;
  const u16* kvg = KV + (size_t)bh * 32 * 8192;
  const float* mptr = mask + b * LL;
  u16* pw = &sP[w][0];
  int t0 = (z < 2) ? z*11 : 22;
  int tn = (z < 2) ? 11 : 10;

  bf16x8 aq[2][2];
  #pragma unroll
  for (int qi = 0; qi < 2; ++qi)
    #pragma unroll
    for (int ks = 0; ks < 2; ++ks)
      aq[qi][ks] = *(const bf16x8*)(QH + qbase + (size_t)(q0 + qi*16 + c) * HD + ks*32 + g*8);

  bf16x8 ones;
  #pragma unroll
  for (int i = 0; i < 8; ++i) ones[i] = (short)0x3F80;   // bf16 1.0

  f32x4 O[2][4], lac[2];
  #pragma unroll
  for (int qi = 0; qi < 2; ++qi) {
    lac[qi] = (f32x4){0.f,0.f,0.f,0.f};
    #pragma unroll
    for (int dt = 0; dt < 4; ++dt) O[qi][dt] = (f32x4){0.f,0.f,0.f,0.f};
  }

  for (int ti = 0; ti < tn; ++ti) {
    int t = t0 + ti;
    __syncthreads();                            // all waves done reading sKV
    #pragma unroll
    for (int it = 0; it < 2; ++it) {            // identity-copy DMA, 16 KB tile, 512 thr
      int i = (tid + it*512) * 8;
      gload_lds16(kvg + (size_t)t*8192 + i, sKV + i);
    }
    __syncthreads();                            // vmcnt(0) drain -> tile ready

    int kv0 = t * 64;
    #pragma unroll
    for (int nt = 0; nt < 4; ++nt) {            // S = Q*V^T, P = exp2(...)
      int vrow = nt*16 + c;
      bf16x8 vb0 = *(const bf16x8*)(sKV + 4096 + vrow*64 + ((g ^ (c & 7))*8));
      bf16x8 vb1 = *(const bf16x8*)(sKV + 4096 + vrow*64 + (((4 + g) ^ (c & 7))*8));
      float mterm = fmaf(mptr[kv0 + vrow], LOG2E, -C_SHIFT);
      #pragma unroll
      for (int qi = 0; qi < 2; ++qi) {
        f32x4 sa = (f32x4){0.f,0.f,0.f,0.f};
        sa = __builtin_amdgcn_mfma_f32_16x16x32_bf16(aq[qi][0], vb0, sa, 0,0,0);
        sa = __builtin_amdgcn_mfma_f32_16x16x32_bf16(aq[qi][1], vb1, sa, 0,0,0);
        #pragma unroll
        for (int r = 0; r < 4; ++r)
          pw[(qi*16 + 4*g + r)*72 + nt*16 + c] = f2bf_trunc(exp2f(fmaf(sa[r], C_QSCALE, mterm)));
      }
    }
    bf16x8 ap[2][2];
    #pragma unroll
    for (int qi = 0; qi < 2; ++qi) {            // P back as B-frags (per-wave, no barrier)
      ap[qi][0] = *(const bf16x8*)(pw + (qi*16 + c)*72 + g*8);
      ap[qi][1] = *(const bf16x8*)(pw + (qi*16 + c)*72 + 32 + g*8);
      lac[qi] = __builtin_amdgcn_mfma_f32_16x16x32_bf16(ones, ap[qi][0], lac[qi], 0,0,0);
      lac[qi] = __builtin_amdgcn_mfma_f32_16x16x32_bf16(ones, ap[qi][1], lac[qi], 0,0,0);
    }
    #pragma unroll
    for (int dt = 0; dt < 4; ++dt) {            // O^T += K^T-frag * P  (d-major out)
      int d = dt*16 + c;
      bf16x8 bk0 = *(const bf16x8*)(sKV + d*64 + ((g ^ (c & 7))*8));
      bf16x8 bk1 = *(const bf16x8*)(sKV + d*64 + (((4 + g) ^ (c & 7))*8));
      #pragma unroll
      for (int qi = 0; qi < 2; ++qi) {
        O[qi][dt] = __builtin_amdgcn_mfma_f32_16x16x32_bf16(bk0, ap[qi][0], O[qi][dt], 0,0,0);
        O[qi][dt] = __builtin_amdgcn_mfma_f32_16x16x32_bf16(bk1, ap[qi][1], O[qi][dt], 0,0,0);
      }
    }
  }
  u16* POp = (z == 0) ? PO0 : (z == 1) ? PO1 : PO2;
  #pragma unroll
  for (int qi = 0; qi < 2; ++qi) {
    int q = q0 + qi*16 + c;
    size_t qrow = (size_t)bh * LL + q;
    if (g == 0) PL[(size_t)(z*32 + bh) * LL + q] = lac[qi][0];   // col-sums: rows equal
    #pragma unroll
    for (int dt = 0; dt < 4; ++dt) {
      u16x4 o;
      #pragma unroll
      for (int r = 0; r < 4; ++r) o[r] = f2bf(O[qi][dt][r]);
      *(u16x4*)(POp + qrow*HD + dt*16 + 4*g) = o;
    }
  }
}

// ---------------- combine key-third partials -> ATT bf16 ----------------
__global__ __launch_bounds__(256) void k_combine(const u16* __restrict__ PO0,
                                                 const u16* __restrict__ PO1,
                                                 const u16* __restrict__ PO2,
                                                 const float* __restrict__ PL,
                                                 u16* __restrict__ ATT) {
  int bh = blockIdx.y, b = bh >> 4, h = bh & 15;
  int q = blockIdx.x * 128 + (threadIdx.x >> 1);
  int dh = (threadIdx.x & 1) * 32;
  size_t r0 = ((size_t)bh * LL + q) * HD + dh;
  float inv = 1.0f / (PL[(size_t)bh * LL + q] + PL[(size_t)(32 + bh) * LL + q]
                    + PL[(size_t)(64 + bh) * LL + q]);
  u16* dst = ATT + ((size_t)(b*LL + q)) * HH + h*HD + dh;
  #pragma unroll
  for (int e = 0; e < 4; ++e) {
    bf16x8 a0 = *(const bf16x8*)(PO0 + r0 + e*8);
    bf16x8 a1 = *(const bf16x8*)(PO1 + r0 + e*8);
    bf16x8 a2 = *(const bf16x8*)(PO2 + r0 + e*8);
    bf16x8 o;
    #pragma unroll
    for (int i = 0; i < 8; ++i)
      o[i] = (short)f2bf((bf2f((u16)a0[i]) + bf2f((u16)a1[i]) + bf2f((u16)a2[i])) * inv);
    *(bf16x8*)(dst + e*8) = o;
  }
}

// ---------------- residual + LayerNorm -> fp32 out ----------------
__global__ __launch_bounds__(256) void k_ln(const float* __restrict__ OF, const float* __restrict__ E,
                                            const float* __restrict__ gamma, const float* __restrict__ beta,
                                            float* __restrict__ out) {
  int row = blockIdx.x;
  int tid = threadIdx.x, lane = tid & 63, w = tid >> 6;
  size_t basei = (size_t)row * HH + tid*4;
  float4 a = *(const float4*)(OF + basei);
  float4 e = *(const float4*)(E + basei);
  float x0 = a.x + e.x, x1 = a.y + e.y, x2 = a.z + e.z, x3 = a.w + e.w;
  float s1 = x0+x1+x2+x3;
  float s2 = x0*x0+x1*x1+x2*x2+x3*x3;
  #pragma unroll
  for (int off = 32; off; off >>= 1) { s1 += __shfl_xor(s1, off); s2 += __shfl_xor(s2, off); }
  __shared__ float r1[4], r2[4];
  if (lane == 0) { r1[w] = s1; r2[w] = s2; }
  __syncthreads();
  s1 = r1[0]+r1[1]+r1[2]+r1[3];
  s2 = r2[0]+r2[1]+r2[2]+r2[3];
  float mu = s1 * (1.0f/HH);
  float var = s2 * (1.0f/HH) - mu*mu;
  float rs = rsqrtf(fmaxf(var, 0.f) + 1e-12f);
  int colb = tid*4;
  float4 gm = *(const float4*)(gamma + colb);
  float4 bt = *(const float4*)(beta + colb);
  float4 o;
  o.x = (x0-mu)*rs*gm.x + bt.x;
  o.y = (x1-mu)*rs*gm.y + bt.y;
  o.z = (x2-mu)*rs*gm.z + bt.z;
  o.w = (x3-mu)*rs*gm.w + bt.w;
  *(float4*)(out + basei) = o;
}

extern "C" void kernel_launch(void* const* d_in, const int* in_sizes, int n_in,
                              void* d_out, int out_size, void* d_ws, size_t ws_size,
                              hipStream_t stream) {
  const float* E    = (const float*)d_in[0];
  const float* mask = (const float*)d_in[1];
  const float* Wq   = (const float*)d_in[2];
  const float* bq   = (const float*)d_in[3];
  const float* Wk   = (const float*)d_in[4];
  const float* bk   = (const float*)d_in[5];
  const float* Wv   = (const float*)d_in[6];
  const float* bv   = (const float*)d_in[7];
  const float* Wo   = (const float*)d_in[8];
  const float* bo   = (const float*)d_in[9];
  const float* gam  = (const float*)d_in[10];
  const float* bet  = (const float*)d_in[11];

  const size_t MH = (size_t)ML * HH;      // 4M elems
  u16* XBF = (u16*)d_ws;                  // 8 MB bf16 embeddings (dead after QKV gemm)
  u16* WT  = XBF + MH;                    // 8 MB: Wq^T,Wk^T,Wv^T,Wo^T bf16 [n][k]
  u16* QH  = WT + 4*(size_t)HH*HH;        // 8 MB, [bh][l][d]
  u16* KV  = QH + MH;                     // 16 MB: [bh][32 tiles][K^T-sw 8KB | V-sw 8KB]
  u16* ATT = KV + 2*MH;                   // 8 MB, [b*L][h*64+d]
  u16* PO0 = ATT + MH;                    // 8 MB partial O, key-third 0
  u16* PO1 = PO0 + MH;                    // 8 MB partial O, key-third 1
  u16* PO2 = XBF;                         // 8 MB partial O, key-third 2 (overlays XBF)
  float* out = (float*)d_out;
  float* PL = out;                        // 768 KB partial l in d_out (k_ln overwrites later)
  float* OF = (float*)PO0;                // 16 MB fp32, overlays PO0+PO1 (dead after combine)

  k_prep<<<dim3(3072), 256, 0, stream>>>(E, XBF, Wq, Wk, Wv, Wo, WT);
  k_gemm<<<dim3(24,32), 256, 0, stream>>>(XBF, WT, bq, bk, bv, QH, KV);
  k_attn<<<dim3(8,3,32), 512, 0, stream>>>(QH, KV, mask, PO0, PO1, PO2, PL);
  k_combine<<<dim3(16,32), 256, 0, stream>>>(PO0, PO1, PO2, PL, ATT);
  k_gemm_o<<<dim3(8,64), 256, 0, stream>>>(ATT, WT + 3*(size_t)HH*HH, bo, OF);
  k_ln<<<dim3(ML), 256, 0, stream>>>(OF, E, gam, bet, out);
}

// Round 11
// 239.041 us; speedup vs baseline: 1.3119x; 1.2634x over previous
//
#include <hip/hip_runtime.h>

#define LOG2E 1.44269504f
#define C_QSCALE 0.360673760f   // 0.25 * log2(e)
#define C_SHIFT  34.6246810f    // 24 * log2(e)
typedef unsigned short u16;
typedef short bf16x8 __attribute__((ext_vector_type(8)));
typedef float f32x4 __attribute__((ext_vector_type(4)));
typedef unsigned short u16x4 __attribute__((ext_vector_type(4)));

#define BB 2
#define LL 2048
#define HH 1024
#define NH 16
#define HD 64
#define ML (BB*LL)   // 4096 rows total

__device__ __forceinline__ u16 f2bf(float f) {   // round-to-nearest-even
  union { float f; unsigned u; } v; v.f = f;
  unsigned r = v.u + 0x7FFFu + ((v.u >> 16) & 1u);
  return (u16)(r >> 16);
}
__device__ __forceinline__ u16 f2bf_trunc(float f) {
  union { float f; unsigned u; } v; v.f = f;
  return (u16)(v.u >> 16);
}
__device__ __forceinline__ float bf2f(u16 u) {
  union { unsigned u; float f; } v; v.u = ((unsigned)u) << 16;
  return v.f;
}
__device__ __forceinline__ void gload_lds16(const u16* g, u16* l) {
  __builtin_amdgcn_global_load_lds((const __attribute__((address_space(1))) void*)g,
                                   (__attribute__((address_space(3))) void*)l, 16, 0, 0);
}

// ---------------- merged: E fp32->bf16 convert  +  W transpose->bf16 ----------------
__global__ __launch_bounds__(256) void k_prep(const float* __restrict__ E, u16* __restrict__ X,
                                              const float* W0, const float* W1,
                                              const float* W2, const float* W3,
                                              u16* __restrict__ WT) {
  __shared__ __align__(16) u16 T[64*72];
  if (blockIdx.x < 2048) {                       // convert branch
    int idx = (blockIdx.x * 256 + threadIdx.x) * 8;
    float4 a = *(const float4*)(E + idx);
    float4 b = *(const float4*)(E + idx + 4);
    bf16x8 o;
    o[0]=f2bf(a.x); o[1]=f2bf(a.y); o[2]=f2bf(a.z); o[3]=f2bf(a.w);
    o[4]=f2bf(b.x); o[5]=f2bf(b.y); o[6]=f2bf(b.z); o[7]=f2bf(b.w);
    *(bf16x8*)(X + idx) = o;
    return;
  }
  int bz = blockIdx.x - 2048;
  int z = bz >> 8, rem = bz & 255, bx = rem & 15, by = rem >> 4;
  const float* W = (z==0)?W0:(z==1)?W1:(z==2)?W2:W3;
  u16* dst = WT + (size_t)z * HH * HH;
  int t = threadIdx.x;
  int n0 = bx * 64, k0 = by * 64;
  int kl = t >> 2, nc = t & 3;
  #pragma unroll
  for (int u = 0; u < 4; ++u) {
    float4 v = *(const float4*)(W + (size_t)(k0 + kl) * HH + n0 + nc*16 + u*4);
    int nb = nc*16 + u*4;
    T[(nb+0)*72 + kl] = f2bf(v.x);
    T[(nb+1)*72 + kl] = f2bf(v.y);
    T[(nb+2)*72 + kl] = f2bf(v.z);
    T[(nb+3)*72 + kl] = f2bf(v.w);
  }
  __syncthreads();
  int nl = t >> 2, kc = (t & 3) * 16;
  #pragma unroll
  for (int e = 0; e < 2; ++e) {
    bf16x8 v = *(const bf16x8*)(T + nl*72 + kc + e*8);
    *(bf16x8*)(dst + (size_t)(n0+nl)*HH + k0 + kc + e*8) = v;
  }
}

// ---------------- 128x128x(K=1024) bf16 QKV GEMM, dbuf DMA prefetch ----
// z=bn0>>10: 0=Q swapped, 1=K normal, 2=V swapped
//   Q -> QH [bh][l][d]; K,V -> KV tiles [bh][t][K^T-sw 8KB | V-sw 8KB]
__global__ __launch_bounds__(256) void k_gemm(const u16* __restrict__ A, const u16* __restrict__ Bt,
                                              const float* __restrict__ b0, const float* __restrict__ b1,
                                              const float* __restrict__ b2,
                                              u16* __restrict__ QH, u16* __restrict__ KV) {
  __shared__ __align__(16) u16 As[2][128*32];
  __shared__ __align__(16) u16 Bs[2][128*32];
  int tid = threadIdx.x;
  int lane = tid & 63, w = tid >> 6;
  int c = lane & 15, g = lane >> 4;
  int bn0 = blockIdx.x * 128, bm0 = blockIdx.y * 128;
  int wm0 = (w >> 1) * 64, wn0 = (w & 1) * 64;
  int z = bn0 >> 10;
  bool swapd = (z != 1);                         // swapped: As<-weights, Bs<-tokens
  const u16* srcA = swapd ? Bt : A;
  const u16* srcB = swapd ? A : Bt;
  int baseA = swapd ? bn0 : bm0;
  int baseB = swapd ? bm0 : bn0;

  f32x4 acc[4][4];
  #pragma unroll
  for (int mt = 0; mt < 4; ++mt)
    #pragma unroll
    for (int nt = 0; nt < 4; ++nt)
      acc[mt][nt] = (f32x4){0.f,0.f,0.f,0.f};

  #pragma unroll
  for (int it = 0; it < 2; ++it) {               // prologue: stage kt=0 -> buf0
    int ch = tid + it*256, row = ch >> 2, col = (ch & 3) * 8;
    gload_lds16(srcA + (size_t)(baseA + row) * HH + col, &As[0][ch*8]);
    gload_lds16(srcB + (size_t)(baseB + row) * HH + col, &Bs[0][ch*8]);
  }
  for (int kt = 0; kt < 32; ++kt) {
    __syncthreads();                             // drains my tile-kt DMA (in flight 1 tile)
    int cb = kt & 1;
    if (kt < 31) {                               // prefetch kt+1 while computing kt
      int k0 = (kt + 1) * 32, nb = (kt + 1) & 1;
      #pragma unroll
      for (int it = 0; it < 2; ++it) {
        int ch = tid + it*256, row = ch >> 2, col = (ch & 3) * 8;
        gload_lds16(srcA + (size_t)(baseA + row) * HH + k0 + col, &As[nb][ch*8]);
        gload_lds16(srcB + (size_t)(baseB + row) * HH + k0 + col, &Bs[nb][ch*8]);
      }
    }
    bf16x8 af[4], bfr[4];
    #pragma unroll
    for (int i = 0; i < 4; ++i) {
      af[i]  = *(const bf16x8*)(&As[cb][0] + (wm0 + i*16 + c)*32 + g*8);
      bfr[i] = *(const bf16x8*)(&Bs[cb][0] + (wn0 + i*16 + c)*32 + g*8);
    }
    #pragma unroll
    for (int mt = 0; mt < 4; ++mt)
      #pragma unroll
      for (int nt = 0; nt < 4; ++nt)
        acc[mt][nt] = __builtin_amdgcn_mfma_f32_16x16x32_bf16(af[mt], bfr[nt], acc[mt][nt], 0, 0, 0);
  }

  if (z == 1) {                                  // K, normal orientation -> K^T-sw tiles
    #pragma unroll
    for (int nt = 0; nt < 4; ++nt) {
      int n = bn0 + wn0 + nt*16 + c;
      int nn = n & 1023, h = nn >> 6, d = nn & 63;
      float bv = b1[nn];
      #pragma unroll
      for (int mt = 0; mt < 4; ++mt) {
        int m0 = bm0 + wm0 + mt*16 + 4*g;
        int b = m0 >> 11, keyl = m0 & 2047;
        int tt = keyl >> 6, chunk = (keyl >> 3) & 7, s = keyl & 7;
        u16x4 pk;
        #pragma unroll
        for (int r = 0; r < 4; ++r) pk[r] = f2bf(acc[mt][nt][r] + bv);
        *(u16x4*)(KV + ((size_t)((b*NH + h)*32 + tt))*8192 + d*64 + ((chunk ^ (d & 7))*8) + s) = pk;
      }
    }
  } else {                                       // Q / V, swapped orientation
    #pragma unroll
    for (int mt = 0; mt < 4; ++mt) {
      int nidx0 = bn0 + wm0 + mt*16 + 4*g;
      int nn0 = nidx0 & 1023, h = nn0 >> 6, d0 = nn0 & 63;
      const float* bp = (z == 0) ? b0 : b2;
      float4 bv = *(const float4*)(bp + nn0);
      #pragma unroll
      for (int nt = 0; nt < 4; ++nt) {
        int tok = bm0 + wn0 + nt*16 + c;
        int b = tok >> 11, l = tok & 2047;
        u16x4 o;
        o[0] = f2bf(acc[mt][nt][0] + bv.x);
        o[1] = f2bf(acc[mt][nt][1] + bv.y);
        o[2] = f2bf(acc[mt][nt][2] + bv.z);
        o[3] = f2bf(acc[mt][nt][3] + bv.w);
        if (z == 0) {
          *(u16x4*)(QH + (((size_t)(b*NH + h)) * LL + l) * HD + d0) = o;
        } else {
          int tt = l >> 6;
          *(u16x4*)(KV + ((size_t)((b*NH + h)*32 + tt))*8192 + 4096
                    + (l & 63)*64 + (((d0 >> 3) ^ (l & 7))*8) + (d0 & 7)) = o;
        }
      }
    }
  }
}

// ---------------- out-proj GEMM: 64 tokens x 128 n per block, dbuf DMA ----------------
__global__ __launch_bounds__(256) void k_gemm_o(const u16* __restrict__ ATT, const u16* __restrict__ Wt,
                                                const float* __restrict__ bias,
                                                float* __restrict__ outf) {
  __shared__ __align__(16) u16 As[2][128*32];    // weights: n rows x k
  __shared__ __align__(16) u16 Bs[2][64*32];     // tokens
  int tid = threadIdx.x;
  int lane = tid & 63, w = tid >> 6;
  int c = lane & 15, g = lane >> 4;
  int bn0 = blockIdx.x * 128, bm0 = blockIdx.y * 64;
  int wm0 = (w >> 1) * 64, wn0 = (w & 1) * 32;

  f32x4 acc[4][2];
  #pragma unroll
  for (int mt = 0; mt < 4; ++mt)
    #pragma unroll
    for (int nt = 0; nt < 2; ++nt)
      acc[mt][nt] = (f32x4){0.f,0.f,0.f,0.f};

  #pragma unroll
  for (int it = 0; it < 2; ++it) {               // prologue: As 512 chunks
    int ch = tid + it*256, row = ch >> 2, col = (ch & 3) * 8;
    gload_lds16(Wt + (size_t)(bn0 + row) * HH + col, &As[0][ch*8]);
  }
  { int row = tid >> 2, col = (tid & 3) * 8;     // Bs 256 chunks
    gload_lds16(ATT + (size_t)(bm0 + row) * HH + col, &Bs[0][tid*8]); }

  for (int kt = 0; kt < 32; ++kt) {
    __syncthreads();
    int cb = kt & 1;
    if (kt < 31) {
      int k0 = (kt + 1) * 32, nb = (kt + 1) & 1;
      #pragma unroll
      for (int it = 0; it < 2; ++it) {
        int ch = tid + it*256, row = ch >> 2, col = (ch & 3) * 8;
        gload_lds16(Wt + (size_t)(bn0 + row) * HH + k0 + col, &As[nb][ch*8]);
      }
      int row = tid >> 2, col = (tid & 3) * 8;
      gload_lds16(ATT + (size_t)(bm0 + row) * HH + k0 + col, &Bs[nb][tid*8]);
    }
    bf16x8 af[4], bfr[2];
    #pragma unroll
    for (int i = 0; i < 4; ++i)
      af[i] = *(const bf16x8*)(&As[cb][0] + (wm0 + i*16 + c)*32 + g*8);
    #pragma unroll
    for (int j = 0; j < 2; ++j)
      bfr[j] = *(const bf16x8*)(&Bs[cb][0] + (wn0 + j*16 + c)*32 + g*8);
    #pragma unroll
    for (int mt = 0; mt < 4; ++mt)
      #pragma unroll
      for (int nt = 0; nt < 2; ++nt)
        acc[mt][nt] = __builtin_amdgcn_mfma_f32_16x16x32_bf16(af[mt], bfr[nt], acc[mt][nt], 0, 0, 0);
  }
  #pragma unroll
  for (int mt = 0; mt < 4; ++mt) {
    int n0 = bn0 + wm0 + mt*16 + 4*g;
    float4 bv = *(const float4*)(bias + n0);
    #pragma unroll
    for (int nt = 0; nt < 2; ++nt) {
      int tok = bm0 + wn0 + nt*16 + c;
      float4 o;
      o.x = acc[mt][nt][0] + bv.x;
      o.y = acc[mt][nt][1] + bv.y;
      o.z = acc[mt][nt][2] + bv.z;
      o.w = acc[mt][nt][3] + bv.w;
      *(float4*)(outf + (size_t)tok * HH + n0) = o;
    }
  }
}

// ---------------- flash attention (r6 config): 256 thr, 4 waves x 32q, key-split x2 ----
// Single-buffer sKV DMA, parallel-qi body, VGPR ~56, 4 blocks/CU, 16 waves/CU.
// Fixed-shift softmax -> partial O (bf16) + l (fp32 in d_out); k_combine normalizes.
__global__ __launch_bounds__(256) void k_attn(const u16* __restrict__ QH, const u16* __restrict__ KV,
                                              const float* __restrict__ mask,
                                              u16* __restrict__ PO0, u16* __restrict__ PO1,
                                              float* __restrict__ PL) {
  __shared__ __align__(16) u16 sKV[8192];       // [0,4096) K^T-sw, [4096,8192) V-sw
  __shared__ __align__(16) u16 sP[4][32*72];
  int tid = threadIdx.x;
  int lane = tid & 63, w = tid >> 6;
  int c = lane & 15, g = lane >> 4;
  int z = blockIdx.y;                           // key half
  int bh = blockIdx.z, b = bh >> 4;
  int q0 = blockIdx.x * 128 + w * 32;           // this wave's 32 q-rows
  size_t qbase = (size_t)bh * LL * HD;
  const u16* kvg = KV + (size_t)bh * 32 * 8192 + (size_t)z * 16 * 8192;
  const float* mptr = mask + b * LL + z * 1024;
  u16* pw = &sP[w][0];

  bf16x8 aq[2][2];
  #pragma unroll
  for (int qi = 0; qi < 2; ++qi)
    #pragma unroll
    for (int ks = 0; ks < 2; ++ks)
      aq[qi][ks] = *(const bf16x8*)(QH + qbase + (size_t)(q0 + qi*16 + c) * HD + ks*32 + g*8);

  bf16x8 ones;
  #pragma unroll
  for (int i = 0; i < 8; ++i) ones[i] = (short)0x3F80;   // bf16 1.0

  f32x4 O[2][4], lac[2];
  #pragma unroll
  for (int qi = 0; qi < 2; ++qi) {
    lac[qi] = (f32x4){0.f,0.f,0.f,0.f};
    #pragma unroll
    for (int dt = 0; dt < 4; ++dt) O[qi][dt] = (f32x4){0.f,0.f,0.f,0.f};
  }

  for (int tt = 0; tt < 16; ++tt) {
    __syncthreads();                            // all waves done reading sKV
    #pragma unroll
    for (int it = 0; it < 4; ++it) {            // identity-copy DMA, 16 KB tile
      int i = (tid + it*256) * 8;
      gload_lds16(kvg + (size_t)tt*8192 + i, sKV + i);
    }
    __syncthreads();                            // vmcnt(0) drain -> tile ready

    int kv0 = tt * 64;
    #pragma unroll
    for (int nt = 0; nt < 4; ++nt) {            // S = Q*V^T, P = exp2(...)
      int vrow = nt*16 + c;
      bf16x8 vb0 = *(const bf16x8*)(sKV + 4096 + vrow*64 + ((g ^ (c & 7))*8));
      bf16x8 vb1 = *(const bf16x8*)(sKV + 4096 + vrow*64 + (((4 + g) ^ (c & 7))*8));
      float mterm = fmaf(mptr[kv0 + vrow], LOG2E, -C_SHIFT);
      #pragma unroll
      for (int qi = 0; qi < 2; ++qi) {
        f32x4 sa = (f32x4){0.f,0.f,0.f,0.f};
        sa = __builtin_amdgcn_mfma_f32_16x16x32_bf16(aq[qi][0], vb0, sa, 0,0,0);
        sa = __builtin_amdgcn_mfma_f32_16x16x32_bf16(aq[qi][1], vb1, sa, 0,0,0);
        #pragma unroll
        for (int r = 0; r < 4; ++r)
          pw[(qi*16 + 4*g + r)*72 + nt*16 + c] = f2bf_trunc(exp2f(fmaf(sa[r], C_QSCALE, mterm)));
      }
    }
    bf16x8 ap[2][2];
    #pragma unroll
    for (int qi = 0; qi < 2; ++qi) {            // P back as B-frags (per-wave, no barrier)
      ap[qi][0] = *(const bf16x8*)(pw + (qi*16 + c)*72 + g*8);
      ap[qi][1] = *(const bf16x8*)(pw + (qi*16 + c)*72 + 32 + g*8);
      lac[qi] = __builtin_amdgcn_mfma_f32_16x16x32_bf16(ones, ap[qi][0], lac[qi], 0,0,0);
      lac[qi] = __builtin_amdgcn_mfma_f32_16x16x32_bf16(ones, ap[qi][1], lac[qi], 0,0,0);
    }
    #pragma unroll
    for (int dt = 0; dt < 4; ++dt) {            // O^T += K^T-frag * P  (d-major out)
      int d = dt*16 + c;
      bf16x8 bk0 = *(const bf16x8*)(sKV + d*64 + ((g ^ (c & 7))*8));
      bf16x8 bk1 = *(const bf16x8*)(sKV + d*64 + (((4 + g) ^ (c & 7))*8));
      #pragma unroll
      for (int qi = 0; qi < 2; ++qi) {
        O[qi][dt] = __builtin_amdgcn_mfma_f32_16x16x32_bf16(bk0, ap[qi][0], O[qi][dt], 0,0,0);
        O[qi][dt] = __builtin_amdgcn_mfma_f32_16x16x32_bf16(bk1, ap[qi][1], O[qi][dt], 0,0,0);
      }
    }
  }
  u16* POp = (z == 0) ? PO0 : PO1;
  #pragma unroll
  for (int qi = 0; qi < 2; ++qi) {
    int q = q0 + qi*16 + c;
    size_t qrow = (size_t)bh * LL + q;
    if (g == 0) PL[(size_t)(z*32 + bh) * LL + q] = lac[qi][0];   // col-sums: rows equal
    #pragma unroll
    for (int dt = 0; dt < 4; ++dt) {
      u16x4 o;
      #pragma unroll
      for (int r = 0; r < 4; ++r) o[r] = f2bf(O[qi][dt][r]);
      *(u16x4*)(POp + qrow*HD + dt*16 + 4*g) = o;
    }
  }
}

// ---------------- combine key-half partials -> ATT bf16 ----------------
__global__ __launch_bounds__(256) void k_combine(const u16* __restrict__ PO0,
                                                 const u16* __restrict__ PO1,
                                                 const float* __restrict__ PL,
                                                 u16* __restrict__ ATT) {
  int bh = blockIdx.y, b = bh >> 4, h = bh & 15;
  int q = blockIdx.x * 128 + (threadIdx.x >> 1);
  int dh = (threadIdx.x & 1) * 32;
  size_t r0 = ((size_t)bh * LL + q) * HD + dh;
  float inv = 1.0f / (PL[(size_t)bh * LL + q] + PL[(size_t)(32 + bh) * LL + q]);
  u16* dst = ATT + ((size_t)(b*LL + q)) * HH + h*HD + dh;
  #pragma unroll
  for (int e = 0; e < 4; ++e) {
    bf16x8 a0 = *(const bf16x8*)(PO0 + r0 + e*8);
    bf16x8 a1 = *(const bf16x8*)(PO1 + r0 + e*8);
    bf16x8 o;
    #pragma unroll
    for (int i = 0; i < 8; ++i)
      o[i] = (short)f2bf((bf2f((u16)a0[i]) + bf2f((u16)a1[i])) * inv);
    *(bf16x8*)(dst + e*8) = o;
  }
}

// ---------------- residual + LayerNorm -> fp32 out ----------------
__global__ __launch_bounds__(256) void k_ln(const float* __restrict__ OF, const float* __restrict__ E,
                                            const float* __restrict__ gamma, const float* __restrict__ beta,
                                            float* __restrict__ out) {
  int row = blockIdx.x;
  int tid = threadIdx.x, lane = tid & 63, w = tid >> 6;
  size_t basei = (size_t)row * HH + tid*4;
  float4 a = *(const float4*)(OF + basei);
  float4 e = *(const float4*)(E + basei);
  float x0 = a.x + e.x, x1 = a.y + e.y, x2 = a.z + e.z, x3 = a.w + e.w;
  float s1 = x0+x1+x2+x3;
  float s2 = x0*x0+x1*x1+x2*x2+x3*x3;
  #pragma unroll
  for (int off = 32; off; off >>= 1) { s1 += __shfl_xor(s1, off); s2 += __shfl_xor(s2, off); }
  __shared__ float r1[4], r2[4];
  if (lane == 0) { r1[w] = s1; r2[w] = s2; }
  __syncthreads();
  s1 = r1[0]+r1[1]+r1[2]+r1[3];
  s2 = r2[0]+r2[1]+r2[2]+r2[3];
  float mu = s1 * (1.0f/HH);
  float var = s2 * (1.0f/HH) - mu*mu;
  float rs = rsqrtf(fmaxf(var, 0.f) + 1e-12f);
  int colb = tid*4;
  float4 gm = *(const float4*)(gamma + colb);
  float4 bt = *(const float4*)(beta + colb);
  float4 o;
  o.x = (x0-mu)*rs*gm.x + bt.x;
  o.y = (x1-mu)*rs*gm.y + bt.y;
  o.z = (x2-mu)*rs*gm.z + bt.z;
  o.w = (x3-mu)*rs*gm.w + bt.w;
  *(float4*)(out + basei) = o;
}

extern "C" void kernel_launch(void* const* d_in, const int* in_sizes, int n_in,
                              void* d_out, int out_size, void* d_ws, size_t ws_size,
                              hipStream_t stream) {
  const float* E    = (const float*)d_in[0];
  const float* mask = (const float*)d_in[1];
  const float* Wq   = (const float*)d_in[2];
  const float* bq   = (const float*)d_in[3];
  const float* Wk   = (const float*)d_in[4];
  const float* bk   = (const float*)d_in[5];
  const float* Wv   = (const float*)d_in[6];
  const float* bv   = (const float*)d_in[7];
  const float* Wo   = (const float*)d_in[8];
  const float* bo   = (const float*)d_in[9];
  const float* gam  = (const float*)d_in[10];
  const float* bet  = (const float*)d_in[11];

  const size_t MH = (size_t)ML * HH;      // 4M elems
  u16* XBF = (u16*)d_ws;                  // 8 MB bf16 embeddings (dead after QKV gemm)
  u16* WT  = XBF + MH;                    // 8 MB: Wq^T,Wk^T,Wv^T,Wo^T bf16 [n][k]
  u16* QH  = WT + 4*(size_t)HH*HH;        // 8 MB, [bh][l][d]
  u16* KV  = QH + MH;                     // 16 MB: [bh][32 tiles][K^T-sw 8KB | V-sw 8KB]
  u16* ATT = KV + 2*MH;                   // 8 MB, [b*L][h*64+d]
  u16* PO0 = ATT + MH;                    // 8 MB partial O, key half 0
  u16* PO1 = PO0 + MH;                    // 8 MB partial O, key half 1
  float* out = (float*)d_out;
  float* PL = out;                        // 512 KB partial l in d_out (k_ln overwrites later)
  float* OF = (float*)PO0;                // 16 MB fp32, overlays PO0+PO1 (dead after combine)

  k_prep<<<dim3(3072), 256, 0, stream>>>(E, XBF, Wq, Wk, Wv, Wo, WT);
  k_gemm<<<dim3(24,32), 256, 0, stream>>>(XBF, WT, bq, bk, bv, QH, KV);
  k_attn<<<dim3(16,2,32), 256, 0, stream>>>(QH, KV, mask, PO0, PO1, PL);
  k_combine<<<dim3(16,32), 256, 0, stream>>>(PO0, PO1, PL, ATT);
  k_gemm_o<<<dim3(8,64), 256, 0, stream>>>(ATT, WT + 3*(size_t)HH*HH, bo, OF);
  k_ln<<<dim3(ML), 256, 0, stream>>>(OF, E, gam, bet, out);
}